// Round 7
// baseline (333.012 us; speedup 1.0000x reference)
//
#include <hip/hip_runtime.h>
#include <hip/hip_bf16.h>

typedef __attribute__((ext_vector_type(4))) float f32x4;
typedef __attribute__((ext_vector_type(8))) short bf16x8;

typedef __attribute__((address_space(1))) unsigned int g_u32;
typedef __attribute__((address_space(3))) unsigned int l_u32;

__device__ __forceinline__ unsigned short f2bf(float f) {
  union { float f; unsigned int u; } v; v.f = f;
  unsigned int u = v.u;
  unsigned int r = (u + 0x7FFFu + ((u >> 16) & 1u)) >> 16;  // RNE
  return (unsigned short)r;
}

// ---------------- prep: pack W1(rows 4..260) and W2 into MFMA-B fragment order ----
__global__ void pack_w_kernel(const float* __restrict__ W1, const float* __restrict__ W2,
                              unsigned short* __restrict__ Bp1, unsigned short* __restrict__ Bp2) {
  int p = blockIdx.x * 256 + threadIdx.x;
  if (p < 32768) {                      // 256x128 for layer 1 (W1 rows 4..260)
    int j = p & 7, n = (p >> 3) & 127, kb = p >> 10;
    Bp1[p] = f2bf(W1[(4 + kb * 8 + j) * 128 + n]);
  } else if (p < 49152) {               // 128x128 for layer 2
    int q = p - 32768;
    int j = q & 7, n = (q >> 3) & 127, kb = q >> 10;
    Bp2[q] = f2bf(W2[(kb * 8 + j) * 128 + n]);
  }
}

// ---------------- prep: x fp32 -> bf16 ----------------
__global__ void convert_x_kernel(const float* __restrict__ x, unsigned short* __restrict__ xb, int n8) {
  int i = blockIdx.x * blockDim.x + threadIdx.x;
  if (i >= n8) return;
  const float4* s = (const float4*)x + (size_t)i * 2;
  float4 a = s[0], b = s[1];
  unsigned short h[8] = {f2bf(a.x), f2bf(a.y), f2bf(a.z), f2bf(a.w),
                         f2bf(b.x), f2bf(b.y), f2bf(b.z), f2bf(b.w)};
  int4 pk; __builtin_memcpy(&pk, h, 16);
  ((int4*)xb)[i] = pk;
}

constexpr int BM = 64;

// ---------------- main kernel: TWO adjacent 64-edge tiles per block, pipelined ----
// R2 config exactly (49 KB LDS -> 3 blocks/CU; scalar consecutive-lane stores; no
// persistence). Traffic rule learned R1-R6: concurrent dirty-output footprint must
// stay < aggregate L2 (4 blocks/CU or persistent grids double WRITE via partial-line
// eviction RMW). Tile1's gather is issued at BAR2 (after tile0's A-reads) and stays
// in flight across tile0's H-write + layer-2 + stores (R3-validated barrier/vmcnt
// discipline) -> one gather-latency exposure removed per 2 tiles; Bp2 frags reused.
__global__ __launch_bounds__(256, 3)
void edge_x2(const unsigned short* __restrict__ xb,
             const float* __restrict__ ea, const int* __restrict__ eidx,
             const float* __restrict__ W1, const float* __restrict__ b1,
             const float* __restrict__ b2,
             const unsigned short* __restrict__ Bp1, const unsigned short* __restrict__ Bp2,
             float* __restrict__ outp, int E, int ntiles) {
  __shared__ int4 AldsV[2048];   // 32 KB  A-tile [64 rows][256 k] bf16
  __shared__ int4 HldsV[1024];   // 16 KB  h [64][128] bf16
  __shared__ float ealds[2][256];

  char* Alds = (char*)AldsV;
  char* Hlds = (char*)HldsV;

  const int tid  = threadIdx.x;
  const int lane = tid & 63;
  const int wq   = lane >> 4;
  const int l16  = lane & 15;
  const int wave = tid >> 6;
  const int g    = tid & 15;
  const int s0   = tid >> 4;

  const int t0 = blockIdx.x * 2;
  const int t1 = t0 + 1;
  const bool has1 = (t1 < ntiles);

  const int c0 = wave * 32 + l16;
  const int c1 = c0 + 16;

  // ---- issue tile0 independent loads first ----
  ealds[0][tid] = ea[t0 * 256 + tid];

  int idx0[8];
  #pragma unroll
  for (int it = 0; it < 8; ++it) {
    int seg = it * 16 + s0;
    idx0[it] = eidx[(seg & 1) * E + t0 * BM + (seg >> 1)];
  }

  // ---- hoisted scalars (latency hides under gather) ----
  const float bias0 = b1[c0], bias1 = b1[c1];
  const float w00 = W1[c0],       w01 = W1[128 + c0], w02 = W1[256 + c0], w03 = W1[384 + c0];
  const float w10 = W1[c1],       w11 = W1[128 + c1], w12 = W1[256 + c1], w13 = W1[384 + c1];
  const float bias20 = b2[c0], bias21 = b2[c1];

  // ---- hoisted layer-1 B fragments (reused for both tiles) ----
  bf16x8 bf1r[8][2];
  #pragma unroll
  for (int ks = 0; ks < 8; ++ks) {
    int kb = ks * 4 + wq;
    bf1r[ks][0] = __builtin_bit_cast(bf16x8, *(const int4*)(Bp1 + ((size_t)kb * 128 + c0) * 8));
    bf1r[ks][1] = __builtin_bit_cast(bf16x8, *(const int4*)(Bp1 + ((size_t)kb * 128 + c1) * 8));
  }

  // ---- gather tile0: async global->LDS, linear dest, pre-swizzled source ----
  #pragma unroll
  for (int it = 0; it < 8; ++it) {
    int seg = it * 16 + s0;
    int r = seg >> 1;
    int gs = g ^ (r & 7);
    const unsigned short* src = xb + (size_t)idx0[it] * 128 + gs * 8;
    char* dstbase = Alds + (it * 16 + wave * 4) * 256;
    __builtin_amdgcn_global_load_lds((g_u32*)(void*)src, (l_u32*)(void*)dstbase, 16, 0, 0);
  }
  __syncthreads();   // TOP0: full drain (compiler emits vmcnt(0) lgkmcnt(0))

  // ---- prefetch tile1 idx + ea (hides under tile0 compute) ----
  int idx1[8];
  if (has1) {
    #pragma unroll
    for (int it = 0; it < 8; ++it) {
      int seg = it * 16 + s0;
      idx1[it] = eidx[(seg & 1) * E + t1 * BM + (seg >> 1)];
    }
    ealds[1][tid] = ea[t1 * 256 + tid];
  }

  // ================= TILE 0 =================
  f32x4 acc[4][2];
  #pragma unroll
  for (int mf = 0; mf < 4; ++mf)
    #pragma unroll
    for (int rg = 0; rg < 4; ++rg) {
      int r = mf * 16 + wq * 4 + rg;
      float e0 = ealds[0][r * 4 + 0], e1 = ealds[0][r * 4 + 1];
      float e2 = ealds[0][r * 4 + 2], e3 = ealds[0][r * 4 + 3];
      acc[mf][0][rg] = bias0 + e0 * w00 + e1 * w01 + e2 * w02 + e3 * w03;
      acc[mf][1][rg] = bias1 + e0 * w10 + e1 * w11 + e2 * w12 + e3 * w13;
    }

  #pragma unroll
  for (int ks = 0; ks < 8; ++ks) {
    #pragma unroll
    for (int mf = 0; mf < 4; ++mf) {
      int r = mf * 16 + l16;
      int lofs = (r * 512 + ks * 64 + wq * 16) ^ ((r & 7) << 4);
      bf16x8 av = __builtin_bit_cast(bf16x8, *(const int4*)(Alds + lofs));
      acc[mf][0] = __builtin_amdgcn_mfma_f32_16x16x32_bf16(av, bf1r[ks][0], acc[mf][0], 0, 0, 0);
      acc[mf][1] = __builtin_amdgcn_mfma_f32_16x16x32_bf16(av, bf1r[ks][1], acc[mf][1], 0, 0, 0);
    }
  }

  // BAR2: all waves done reading A -> safe to overwrite with tile1 gather
  asm volatile("s_waitcnt lgkmcnt(0)" ::: "memory");
  __builtin_amdgcn_s_barrier();

  // issue tile1 gather NOW; stays in flight across H-write/layer-2/stores
  if (has1) {
    #pragma unroll
    for (int it = 0; it < 8; ++it) {
      int seg = it * 16 + s0;
      int r = seg >> 1;
      int gs = g ^ (r & 7);
      const unsigned short* src = xb + (size_t)idx1[it] * 128 + gs * 8;
      char* dstbase = Alds + (it * 16 + wave * 4) * 256;
      __builtin_amdgcn_global_load_lds((g_u32*)(void*)src, (l_u32*)(void*)dstbase, 16, 0, 0);
    }
  }

  // layer-2 B fragments (loaded once, reused for both tiles)
  bf16x8 bf2r[4][2];
  #pragma unroll
  for (int ks = 0; ks < 4; ++ks) {
    int kb = ks * 4 + wq;
    bf2r[ks][0] = __builtin_bit_cast(bf16x8, *(const int4*)(Bp2 + ((size_t)kb * 128 + c0) * 8));
    bf2r[ks][1] = __builtin_bit_cast(bf16x8, *(const int4*)(Bp2 + ((size_t)kb * 128 + c1) * 8));
  }

  // ReLU + h -> Hlds (bf16, swizzled)
  #pragma unroll
  for (int mf = 0; mf < 4; ++mf)
    #pragma unroll
    for (int nf = 0; nf < 2; ++nf) {
      int c = wave * 32 + nf * 16 + l16;
      #pragma unroll
      for (int rg = 0; rg < 4; ++rg) {
        int r = mf * 16 + wq * 4 + rg;
        float v = fmaxf(acc[mf][nf][rg], 0.0f);
        int lofs = (r * 256 + c * 2) ^ ((r & 7) << 4);
        *(unsigned short*)(Hlds + lofs) = f2bf(v);
      }
    }

  // BAR3: H visible (LDS only — tile1 gather stays in flight)
  asm volatile("s_waitcnt lgkmcnt(0)" ::: "memory");
  __builtin_amdgcn_s_barrier();

  f32x4 acc2[4][2];
  #pragma unroll
  for (int mf = 0; mf < 4; ++mf) {
    acc2[mf][0] = (f32x4){bias20, bias20, bias20, bias20};
    acc2[mf][1] = (f32x4){bias21, bias21, bias21, bias21};
  }
  #pragma unroll
  for (int ks = 0; ks < 4; ++ks) {
    #pragma unroll
    for (int mf = 0; mf < 4; ++mf) {
      int r = mf * 16 + l16;
      int lofs = (r * 256 + ks * 64 + wq * 16) ^ ((r & 7) << 4);
      bf16x8 av = __builtin_bit_cast(bf16x8, *(const int4*)(Hlds + lofs));
      acc2[mf][0] = __builtin_amdgcn_mfma_f32_16x16x32_bf16(av, bf2r[ks][0], acc2[mf][0], 0, 0, 0);
      acc2[mf][1] = __builtin_amdgcn_mfma_f32_16x16x32_bf16(av, bf2r[ks][1], acc2[mf][1], 0, 0, 0);
    }
  }

  // epilogue tile0: scalar stores, consecutive lanes -> consecutive addresses
  #pragma unroll
  for (int mf = 0; mf < 4; ++mf)
    #pragma unroll
    for (int nf = 0; nf < 2; ++nf) {
      int c = wave * 32 + nf * 16 + l16;
      #pragma unroll
      for (int rg = 0; rg < 4; ++rg) {
        int r = mf * 16 + wq * 4 + rg;
        outp[(size_t)(t0 * BM + r) * 128 + c] = acc2[mf][nf][rg];
      }
    }

  // ================= TILE 1 =================
  if (has1) {
    // TOP1: tile1 gathers complete (also drains tile0 stores; barrier syncs waves)
    asm volatile("s_waitcnt vmcnt(0) lgkmcnt(0)" ::: "memory");
    __builtin_amdgcn_s_barrier();

    #pragma unroll
    for (int mf = 0; mf < 4; ++mf)
      #pragma unroll
      for (int rg = 0; rg < 4; ++rg) {
        int r = mf * 16 + wq * 4 + rg;
        float e0 = ealds[1][r * 4 + 0], e1 = ealds[1][r * 4 + 1];
        float e2 = ealds[1][r * 4 + 2], e3 = ealds[1][r * 4 + 3];
        acc[mf][0][rg] = bias0 + e0 * w00 + e1 * w01 + e2 * w02 + e3 * w03;
        acc[mf][1][rg] = bias1 + e0 * w10 + e1 * w11 + e2 * w12 + e3 * w13;
      }

    #pragma unroll
    for (int ks = 0; ks < 8; ++ks) {
      #pragma unroll
      for (int mf = 0; mf < 4; ++mf) {
        int r = mf * 16 + l16;
        int lofs = (r * 512 + ks * 64 + wq * 16) ^ ((r & 7) << 4);
        bf16x8 av = __builtin_bit_cast(bf16x8, *(const int4*)(Alds + lofs));
        acc[mf][0] = __builtin_amdgcn_mfma_f32_16x16x32_bf16(av, bf1r[ks][0], acc[mf][0], 0, 0, 0);
        acc[mf][1] = __builtin_amdgcn_mfma_f32_16x16x32_bf16(av, bf1r[ks][1], acc[mf][1], 0, 0, 0);
      }
    }

    // H1 -> Hlds: all Hlds reads (tile0 layer-2) finished before TOP1 barrier,
    // and H1 writes only touch Hlds (not Alds) -> no extra barrier needed here.
    #pragma unroll
    for (int mf = 0; mf < 4; ++mf)
      #pragma unroll
      for (int nf = 0; nf < 2; ++nf) {
        int c = wave * 32 + nf * 16 + l16;
        #pragma unroll
        for (int rg = 0; rg < 4; ++rg) {
          int r = mf * 16 + wq * 4 + rg;
          float v = fmaxf(acc[mf][nf][rg], 0.0f);
          int lofs = (r * 256 + c * 2) ^ ((r & 7) << 4);
          *(unsigned short*)(Hlds + lofs) = f2bf(v);
        }
      }

    // BAR3b: H1 visible
    asm volatile("s_waitcnt lgkmcnt(0)" ::: "memory");
    __builtin_amdgcn_s_barrier();

    f32x4 acc2b[4][2];
    #pragma unroll
    for (int mf = 0; mf < 4; ++mf) {
      acc2b[mf][0] = (f32x4){bias20, bias20, bias20, bias20};
      acc2b[mf][1] = (f32x4){bias21, bias21, bias21, bias21};
    }
    #pragma unroll
    for (int ks = 0; ks < 4; ++ks) {
      #pragma unroll
      for (int mf = 0; mf < 4; ++mf) {
        int r = mf * 16 + l16;
        int lofs = (r * 256 + ks * 64 + wq * 16) ^ ((r & 7) << 4);
        bf16x8 av = __builtin_bit_cast(bf16x8, *(const int4*)(Hlds + lofs));
        acc2b[mf][0] = __builtin_amdgcn_mfma_f32_16x16x32_bf16(av, bf2r[ks][0], acc2b[mf][0], 0, 0, 0);
        acc2b[mf][1] = __builtin_amdgcn_mfma_f32_16x16x32_bf16(av, bf2r[ks][1], acc2b[mf][1], 0, 0, 0);
      }
    }

    #pragma unroll
    for (int mf = 0; mf < 4; ++mf)
      #pragma unroll
      for (int nf = 0; nf < 2; ++nf) {
        int c = wave * 32 + nf * 16 + l16;
        #pragma unroll
        for (int rg = 0; rg < 4; ++rg) {
          int r = mf * 16 + wq * 4 + rg;
          outp[(size_t)(t1 * BM + r) * 128 + c] = acc2b[mf][nf][rg];
        }
      }
  }
}

// ---------------- fallback (fp32 gather, non-persistent) for small ws ----------------
__global__ __launch_bounds__(256, 3)
void edge_main_f32(const float* __restrict__ xf,
                   const float* __restrict__ ea, const int* __restrict__ eidx,
                   const float* __restrict__ W1, const float* __restrict__ b1,
                   const float* __restrict__ b2,
                   const unsigned short* __restrict__ Bp1, const unsigned short* __restrict__ Bp2,
                   float* __restrict__ outp, int E) {
  __shared__ int4 AldsV[2048];
  __shared__ int4 HldsV[1024];
  __shared__ float ealds[256];
  char* Alds = (char*)AldsV;
  char* Hlds = (char*)HldsV;

  const int tid  = threadIdx.x;
  const int lane = tid & 63;
  const int wq   = lane >> 4;
  const int l16  = lane & 15;
  const int wave = tid >> 6;
  const int eb   = blockIdx.x * BM;

  ealds[tid] = ea[eb * 4 + tid];

  const int g  = tid & 15;
  const int s0 = tid >> 4;

  int idxv[8];
  #pragma unroll
  for (int it = 0; it < 8; ++it) {
    int seg = it * 16 + s0;
    idxv[it] = eidx[(seg & 1) * E + eb + (seg >> 1)];
  }

  const int c0 = wave * 32 + l16;
  const int c1 = c0 + 16;
  const float bias0 = b1[c0], bias1 = b1[c1];
  const float w00 = W1[c0],       w01 = W1[128 + c0], w02 = W1[256 + c0], w03 = W1[384 + c0];
  const float w10 = W1[c1],       w11 = W1[128 + c1], w12 = W1[256 + c1], w13 = W1[384 + c1];
  const float bias20 = b2[c0], bias21 = b2[c1];

  bf16x8 bf1r[8][2];
  #pragma unroll
  for (int ks = 0; ks < 8; ++ks) {
    int kb = ks * 4 + wq;
    bf1r[ks][0] = __builtin_bit_cast(bf16x8, *(const int4*)(Bp1 + ((size_t)kb * 128 + c0) * 8));
    bf1r[ks][1] = __builtin_bit_cast(bf16x8, *(const int4*)(Bp1 + ((size_t)kb * 128 + c1) * 8));
  }

  #pragma unroll
  for (int it = 0; it < 8; ++it) {
    int seg = it * 16 + s0;
    int r = seg >> 1, half = seg & 1;
    int lofs = (r * 512 + half * 256 + g * 16) ^ ((r & 7) << 4);
    const float* src = xf + (size_t)idxv[it] * 128 + g * 8;
    float4 a = *(const float4*)src;
    float4 c = *(const float4*)(src + 4);
    unsigned short h[8] = {f2bf(a.x), f2bf(a.y), f2bf(a.z), f2bf(a.w),
                           f2bf(c.x), f2bf(c.y), f2bf(c.z), f2bf(c.w)};
    int4 pk; __builtin_memcpy(&pk, h, 16);
    *(int4*)(Alds + lofs) = pk;
  }
  __syncthreads();

  f32x4 acc[4][2];
  #pragma unroll
  for (int mf = 0; mf < 4; ++mf)
    #pragma unroll
    for (int rg = 0; rg < 4; ++rg) {
      int r = mf * 16 + wq * 4 + rg;
      float e0 = ealds[r * 4 + 0], e1 = ealds[r * 4 + 1];
      float e2 = ealds[r * 4 + 2], e3 = ealds[r * 4 + 3];
      acc[mf][0][rg] = bias0 + e0 * w00 + e1 * w01 + e2 * w02 + e3 * w03;
      acc[mf][1][rg] = bias1 + e0 * w10 + e1 * w11 + e2 * w12 + e3 * w13;
    }

  #pragma unroll
  for (int ks = 0; ks < 8; ++ks)
    #pragma unroll
    for (int mf = 0; mf < 4; ++mf) {
      int r = mf * 16 + l16;
      int lofs = (r * 512 + ks * 64 + wq * 16) ^ ((r & 7) << 4);
      bf16x8 av = __builtin_bit_cast(bf16x8, *(const int4*)(Alds + lofs));
      acc[mf][0] = __builtin_amdgcn_mfma_f32_16x16x32_bf16(av, bf1r[ks][0], acc[mf][0], 0, 0, 0);
      acc[mf][1] = __builtin_amdgcn_mfma_f32_16x16x32_bf16(av, bf1r[ks][1], acc[mf][1], 0, 0, 0);
    }

  bf16x8 bf2r[4][2];
  #pragma unroll
  for (int ks = 0; ks < 4; ++ks) {
    int kb = ks * 4 + wq;
    bf2r[ks][0] = __builtin_bit_cast(bf16x8, *(const int4*)(Bp2 + ((size_t)kb * 128 + c0) * 8));
    bf2r[ks][1] = __builtin_bit_cast(bf16x8, *(const int4*)(Bp2 + ((size_t)kb * 128 + c1) * 8));
  }

  #pragma unroll
  for (int mf = 0; mf < 4; ++mf)
    #pragma unroll
    for (int nf = 0; nf < 2; ++nf) {
      int c = wave * 32 + nf * 16 + l16;
      #pragma unroll
      for (int rg = 0; rg < 4; ++rg) {
        int r = mf * 16 + wq * 4 + rg;
        float v = fmaxf(acc[mf][nf][rg], 0.0f);
        int lofs = (r * 256 + c * 2) ^ ((r & 7) << 4);
        *(unsigned short*)(Hlds + lofs) = f2bf(v);
      }
    }
  __syncthreads();

  f32x4 acc2[4][2];
  #pragma unroll
  for (int mf = 0; mf < 4; ++mf) {
    acc2[mf][0] = (f32x4){bias20, bias20, bias20, bias20};
    acc2[mf][1] = (f32x4){bias21, bias21, bias21, bias21};
  }
  #pragma unroll
  for (int ks = 0; ks < 4; ++ks)
    #pragma unroll
    for (int mf = 0; mf < 4; ++mf) {
      int r = mf * 16 + l16;
      int lofs = (r * 256 + ks * 64 + wq * 16) ^ ((r & 7) << 4);
      bf16x8 av = __builtin_bit_cast(bf16x8, *(const int4*)(Hlds + lofs));
      acc2[mf][0] = __builtin_amdgcn_mfma_f32_16x16x32_bf16(av, bf2r[ks][0], acc2[mf][0], 0, 0, 0);
      acc2[mf][1] = __builtin_amdgcn_mfma_f32_16x16x32_bf16(av, bf2r[ks][1], acc2[mf][1], 0, 0, 0);
    }

  #pragma unroll
  for (int mf = 0; mf < 4; ++mf)
    #pragma unroll
    for (int nf = 0; nf < 2; ++nf) {
      int c = wave * 32 + nf * 16 + l16;
      #pragma unroll
      for (int rg = 0; rg < 4; ++rg) {
        int r = mf * 16 + wq * 4 + rg;
        outp[(size_t)(eb + r) * 128 + c] = acc2[mf][nf][rg];
      }
    }
}

extern "C" void kernel_launch(void* const* d_in, const int* in_sizes, int n_in,
                              void* d_out, int out_size, void* d_ws, size_t ws_size,
                              hipStream_t stream) {
  const float* x  = (const float*)d_in[0];
  const float* ea = (const float*)d_in[1];
  const int* eidx = (const int*)d_in[2];
  const float* W1 = (const float*)d_in[3];
  const float* b1 = (const float*)d_in[4];
  const float* W2 = (const float*)d_in[5];
  const float* b2 = (const float*)d_in[6];
  float* outp = (float*)d_out;

  const int E = in_sizes[2] / 2;
  const int nnodes = in_sizes[0] / 128;
  const int ntiles = E / BM;

  unsigned short* Bp1 = (unsigned short*)d_ws;           // 64 KB
  unsigned short* Bp2 = Bp1 + 32768;                     // 32 KB
  unsigned short* xb  = (unsigned short*)((char*)d_ws + 98304);
  const size_t need = 98304 + (size_t)nnodes * 128 * 2;

  pack_w_kernel<<<192, 256, 0, stream>>>(W1, W2, Bp1, Bp2);

  if (ws_size >= need) {
    int n8 = nnodes * 128 / 8;
    convert_x_kernel<<<(n8 + 255) / 256, 256, 0, stream>>>(x, xb, n8);
    int nblk = (ntiles + 1) / 2;
    edge_x2<<<nblk, 256, 0, stream>>>(xb, ea, eidx, W1, b1, b2, Bp1, Bp2, outp, E, ntiles);
  } else {
    edge_main_f32<<<ntiles, 256, 0, stream>>>(x, ea, eidx, W1, b1, b2, Bp1, Bp2, outp, E);
  }
}

// Round 8
// 155.004 us; speedup vs baseline: 2.1484x; 2.1484x over previous
//
#include <hip/hip_runtime.h>
#include <hip/hip_bf16.h>

typedef __attribute__((ext_vector_type(4))) float f32x4;
typedef __attribute__((ext_vector_type(8))) short bf16x8;

__device__ __forceinline__ unsigned short f2bf(float f) {
  union { float f; unsigned int u; } v; v.f = f;
  unsigned int u = v.u;
  unsigned int r = (u + 0x7FFFu + ((u >> 16) & 1u)) >> 16;  // RNE
  return (unsigned short)r;
}

// ---------------- prep: pack W1(rows 4..260) and W2 into MFMA-B fragment order ----
__global__ void pack_w_kernel(const float* __restrict__ W1, const float* __restrict__ W2,
                              unsigned short* __restrict__ Bp1, unsigned short* __restrict__ Bp2) {
  int p = blockIdx.x * 256 + threadIdx.x;
  if (p < 32768) {                      // 256x128 for layer 1 (W1 rows 4..260)
    int j = p & 7, n = (p >> 3) & 127, kb = p >> 10;
    Bp1[p] = f2bf(W1[(4 + kb * 8 + j) * 128 + n]);
  } else if (p < 49152) {               // 128x128 for layer 2
    int q = p - 32768;
    int j = q & 7, n = (q >> 3) & 127, kb = q >> 10;
    Bp2[q] = f2bf(W2[(kb * 8 + j) * 128 + n]);
  }
}

// ---------------- prep: x fp32 -> bf16 ----------------
__global__ void convert_x_kernel(const float* __restrict__ x, unsigned short* __restrict__ xb, int n8) {
  int i = blockIdx.x * blockDim.x + threadIdx.x;
  if (i >= n8) return;
  const float4* s = (const float4*)x + (size_t)i * 2;
  float4 a = s[0], b = s[1];
  unsigned short h[8] = {f2bf(a.x), f2bf(a.y), f2bf(a.z), f2bf(a.w),
                         f2bf(b.x), f2bf(b.y), f2bf(b.z), f2bf(b.w)};
  int4 pk; __builtin_memcpy(&pk, h, 16);
  ((int4*)xb)[i] = pk;
}

constexpr int BM = 64;

// ---------------- main fused kernel: one 64-edge tile per block ----------------
// R2 structure (hoisted B-frags + idx prefetch, 49 KB LDS, 3 blocks/CU) but gather
// uses NORMAL vector loads -> VGPR -> ds_write_b128 (R1's mode). Evidence R1-R7:
// every global_load_lds kernel showed FETCH ~= full no-reuse gather volume (327 MB)
// and ~2x WRITE (streaming/non-allocating L2 reads starve x-reuse and write-combine);
// R1's normal-load gather measured exactly 320 MB WRITE / 157 MB FETCH. The staged
// gather's load latency hides under the (independent) hoisted B-frag loads.
__global__ __launch_bounds__(256, 3)
void edge_staged(const unsigned short* __restrict__ xb,
                 const float* __restrict__ ea, const int* __restrict__ eidx,
                 const float* __restrict__ W1, const float* __restrict__ b1,
                 const float* __restrict__ b2,
                 const unsigned short* __restrict__ Bp1, const unsigned short* __restrict__ Bp2,
                 float* __restrict__ outp, int E) {
  __shared__ int4 AldsV[2048];   // 32 KB  A-tile [64 rows][256 k] bf16, XOR-swizzled
  __shared__ int4 HldsV[1024];   // 16 KB  h [64][128] bf16, XOR-swizzled
  __shared__ float ealds[256];   // 64 edges x 4 attrs

  char* Alds = (char*)AldsV;
  char* Hlds = (char*)HldsV;

  const int tid  = threadIdx.x;
  const int lane = tid & 63;
  const int wq   = lane >> 4;
  const int l16  = lane & 15;
  const int wave = tid >> 6;
  const int g    = tid & 15;
  const int s0   = tid >> 4;
  const int eb   = blockIdx.x * BM;

  // ---- issue independent loads first: edge_attr, eidx ----
  ealds[tid] = ea[eb * 4 + tid];

  int idxv[8];
  #pragma unroll
  for (int it = 0; it < 8; ++it) {
    int seg = it * 16 + s0;
    idxv[it] = eidx[(seg & 1) * E + eb + (seg >> 1)];
  }

  // ---- gather loads: normal (L2-allocating) int4 loads into VGPRs ----
  int4 gv[8];
  #pragma unroll
  for (int it = 0; it < 8; ++it)
    gv[it] = *(const int4*)(xb + (size_t)idxv[it] * 128 + g * 8);

  const int c0 = wave * 32 + l16;
  const int c1 = c0 + 16;

  // ---- hoisted scalars + layer-1 B fragments (latency overlaps gather) ----
  const float bias0 = b1[c0], bias1 = b1[c1];
  const float w00 = W1[c0],       w01 = W1[128 + c0], w02 = W1[256 + c0], w03 = W1[384 + c0];
  const float w10 = W1[c1],       w11 = W1[128 + c1], w12 = W1[256 + c1], w13 = W1[384 + c1];
  const float bias20 = b2[c0], bias21 = b2[c1];

  bf16x8 bf1r[8][2];
  #pragma unroll
  for (int ks = 0; ks < 8; ++ks) {
    int kb = ks * 4 + wq;
    bf1r[ks][0] = __builtin_bit_cast(bf16x8, *(const int4*)(Bp1 + ((size_t)kb * 128 + c0) * 8));
    bf1r[ks][1] = __builtin_bit_cast(bf16x8, *(const int4*)(Bp1 + ((size_t)kb * 128 + c1) * 8));
  }

  // ---- stage gather into LDS (XOR-swizzled dest, b128 writes) ----
  #pragma unroll
  for (int it = 0; it < 8; ++it) {
    int seg = it * 16 + s0;
    int r = seg >> 1, half = seg & 1;
    int lofs = (r * 512 + half * 256 + g * 16) ^ ((r & 7) << 4);
    *(int4*)(Alds + lofs) = gv[it];
  }
  __syncthreads();

  // ---- layer 1 accumulator init: b1 + edge_attr x W1[0:4] in fp32 ----
  f32x4 acc[4][2];
  #pragma unroll
  for (int mf = 0; mf < 4; ++mf)
    #pragma unroll
    for (int rg = 0; rg < 4; ++rg) {
      int r = mf * 16 + wq * 4 + rg;
      float e0 = ealds[r * 4 + 0], e1 = ealds[r * 4 + 1];
      float e2 = ealds[r * 4 + 2], e3 = ealds[r * 4 + 3];
      acc[mf][0][rg] = bias0 + e0 * w00 + e1 * w01 + e2 * w02 + e3 * w03;
      acc[mf][1][rg] = bias1 + e0 * w10 + e1 * w11 + e2 * w12 + e3 * w13;
    }

  // ---- layer 1 MFMA: K = 256 (sender 128 | receiver 128), B from registers ----
  #pragma unroll
  for (int ks = 0; ks < 8; ++ks) {
    #pragma unroll
    for (int mf = 0; mf < 4; ++mf) {
      int r = mf * 16 + l16;
      int lofs = (r * 512 + ks * 64 + wq * 16) ^ ((r & 7) << 4);
      bf16x8 av = __builtin_bit_cast(bf16x8, *(const int4*)(Alds + lofs));
      acc[mf][0] = __builtin_amdgcn_mfma_f32_16x16x32_bf16(av, bf1r[ks][0], acc[mf][0], 0, 0, 0);
      acc[mf][1] = __builtin_amdgcn_mfma_f32_16x16x32_bf16(av, bf1r[ks][1], acc[mf][1], 0, 0, 0);
    }
  }

  // ---- layer-2 B fragments: issue now, latency hides under H-write + barrier ----
  bf16x8 bf2r[4][2];
  #pragma unroll
  for (int ks = 0; ks < 4; ++ks) {
    int kb = ks * 4 + wq;
    bf2r[ks][0] = __builtin_bit_cast(bf16x8, *(const int4*)(Bp2 + ((size_t)kb * 128 + c0) * 8));
    bf2r[ks][1] = __builtin_bit_cast(bf16x8, *(const int4*)(Bp2 + ((size_t)kb * 128 + c1) * 8));
  }

  // ---- ReLU + h -> LDS (bf16, swizzled) ----
  #pragma unroll
  for (int mf = 0; mf < 4; ++mf)
    #pragma unroll
    for (int nf = 0; nf < 2; ++nf) {
      int c = wave * 32 + nf * 16 + l16;
      #pragma unroll
      for (int rg = 0; rg < 4; ++rg) {
        int r = mf * 16 + wq * 4 + rg;
        float v = fmaxf(acc[mf][nf][rg], 0.0f);
        int lofs = (r * 256 + c * 2) ^ ((r & 7) << 4);
        *(unsigned short*)(Hlds + lofs) = f2bf(v);
      }
    }
  __syncthreads();

  // ---- layer 2: K = 128 ----
  f32x4 acc2[4][2];
  #pragma unroll
  for (int mf = 0; mf < 4; ++mf) {
    acc2[mf][0] = (f32x4){bias20, bias20, bias20, bias20};
    acc2[mf][1] = (f32x4){bias21, bias21, bias21, bias21};
  }
  #pragma unroll
  for (int ks = 0; ks < 4; ++ks) {
    #pragma unroll
    for (int mf = 0; mf < 4; ++mf) {
      int r = mf * 16 + l16;
      int lofs = (r * 256 + ks * 64 + wq * 16) ^ ((r & 7) << 4);
      bf16x8 av = __builtin_bit_cast(bf16x8, *(const int4*)(Hlds + lofs));
      acc2[mf][0] = __builtin_amdgcn_mfma_f32_16x16x32_bf16(av, bf2r[ks][0], acc2[mf][0], 0, 0, 0);
      acc2[mf][1] = __builtin_amdgcn_mfma_f32_16x16x32_bf16(av, bf2r[ks][1], acc2[mf][1], 0, 0, 0);
    }
  }

  // ---- epilogue: scalar stores, consecutive lanes -> consecutive addresses ----
  #pragma unroll
  for (int mf = 0; mf < 4; ++mf)
    #pragma unroll
    for (int nf = 0; nf < 2; ++nf) {
      int c = wave * 32 + nf * 16 + l16;
      #pragma unroll
      for (int rg = 0; rg < 4; ++rg) {
        int r = mf * 16 + wq * 4 + rg;
        outp[(size_t)(eb + r) * 128 + c] = acc2[mf][nf][rg];
      }
    }
}

// ---------------- fallback (fp32 gather, non-persistent) for small ws ----------------
__global__ __launch_bounds__(256, 3)
void edge_main_f32(const float* __restrict__ xf,
                   const float* __restrict__ ea, const int* __restrict__ eidx,
                   const float* __restrict__ W1, const float* __restrict__ b1,
                   const float* __restrict__ b2,
                   const unsigned short* __restrict__ Bp1, const unsigned short* __restrict__ Bp2,
                   float* __restrict__ outp, int E) {
  __shared__ int4 AldsV[2048];
  __shared__ int4 HldsV[1024];
  __shared__ float ealds[256];
  char* Alds = (char*)AldsV;
  char* Hlds = (char*)HldsV;

  const int tid  = threadIdx.x;
  const int lane = tid & 63;
  const int wq   = lane >> 4;
  const int l16  = lane & 15;
  const int wave = tid >> 6;
  const int eb   = blockIdx.x * BM;

  ealds[tid] = ea[eb * 4 + tid];

  const int g  = tid & 15;
  const int s0 = tid >> 4;

  int idxv[8];
  #pragma unroll
  for (int it = 0; it < 8; ++it) {
    int seg = it * 16 + s0;
    idxv[it] = eidx[(seg & 1) * E + eb + (seg >> 1)];
  }

  const int c0 = wave * 32 + l16;
  const int c1 = c0 + 16;
  const float bias0 = b1[c0], bias1 = b1[c1];
  const float w00 = W1[c0],       w01 = W1[128 + c0], w02 = W1[256 + c0], w03 = W1[384 + c0];
  const float w10 = W1[c1],       w11 = W1[128 + c1], w12 = W1[256 + c1], w13 = W1[384 + c1];
  const float bias20 = b2[c0], bias21 = b2[c1];

  bf16x8 bf1r[8][2];
  #pragma unroll
  for (int ks = 0; ks < 8; ++ks) {
    int kb = ks * 4 + wq;
    bf1r[ks][0] = __builtin_bit_cast(bf16x8, *(const int4*)(Bp1 + ((size_t)kb * 128 + c0) * 8));
    bf1r[ks][1] = __builtin_bit_cast(bf16x8, *(const int4*)(Bp1 + ((size_t)kb * 128 + c1) * 8));
  }

  #pragma unroll
  for (int it = 0; it < 8; ++it) {
    int seg = it * 16 + s0;
    int r = seg >> 1, half = seg & 1;
    int lofs = (r * 512 + half * 256 + g * 16) ^ ((r & 7) << 4);
    const float* src = xf + (size_t)idxv[it] * 128 + g * 8;
    float4 a = *(const float4*)src;
    float4 c = *(const float4*)(src + 4);
    unsigned short h[8] = {f2bf(a.x), f2bf(a.y), f2bf(a.z), f2bf(a.w),
                           f2bf(c.x), f2bf(c.y), f2bf(c.z), f2bf(c.w)};
    int4 pk; __builtin_memcpy(&pk, h, 16);
    *(int4*)(Alds + lofs) = pk;
  }
  __syncthreads();

  f32x4 acc[4][2];
  #pragma unroll
  for (int mf = 0; mf < 4; ++mf)
    #pragma unroll
    for (int rg = 0; rg < 4; ++rg) {
      int r = mf * 16 + wq * 4 + rg;
      float e0 = ealds[r * 4 + 0], e1 = ealds[r * 4 + 1];
      float e2 = ealds[r * 4 + 2], e3 = ealds[r * 4 + 3];
      acc[mf][0][rg] = bias0 + e0 * w00 + e1 * w01 + e2 * w02 + e3 * w03;
      acc[mf][1][rg] = bias1 + e0 * w10 + e1 * w11 + e2 * w12 + e3 * w13;
    }

  #pragma unroll
  for (int ks = 0; ks < 8; ++ks)
    #pragma unroll
    for (int mf = 0; mf < 4; ++mf) {
      int r = mf * 16 + l16;
      int lofs = (r * 512 + ks * 64 + wq * 16) ^ ((r & 7) << 4);
      bf16x8 av = __builtin_bit_cast(bf16x8, *(const int4*)(Alds + lofs));
      acc[mf][0] = __builtin_amdgcn_mfma_f32_16x16x32_bf16(av, bf1r[ks][0], acc[mf][0], 0, 0, 0);
      acc[mf][1] = __builtin_amdgcn_mfma_f32_16x16x32_bf16(av, bf1r[ks][1], acc[mf][1], 0, 0, 0);
    }

  bf16x8 bf2r[4][2];
  #pragma unroll
  for (int ks = 0; ks < 4; ++ks) {
    int kb = ks * 4 + wq;
    bf2r[ks][0] = __builtin_bit_cast(bf16x8, *(const int4*)(Bp2 + ((size_t)kb * 128 + c0) * 8));
    bf2r[ks][1] = __builtin_bit_cast(bf16x8, *(const int4*)(Bp2 + ((size_t)kb * 128 + c1) * 8));
  }

  #pragma unroll
  for (int mf = 0; mf < 4; ++mf)
    #pragma unroll
    for (int nf = 0; nf < 2; ++nf) {
      int c = wave * 32 + nf * 16 + l16;
      #pragma unroll
      for (int rg = 0; rg < 4; ++rg) {
        int r = mf * 16 + wq * 4 + rg;
        float v = fmaxf(acc[mf][nf][rg], 0.0f);
        int lofs = (r * 256 + c * 2) ^ ((r & 7) << 4);
        *(unsigned short*)(Hlds + lofs) = f2bf(v);
      }
    }
  __syncthreads();

  f32x4 acc2[4][2];
  #pragma unroll
  for (int mf = 0; mf < 4; ++mf) {
    acc2[mf][0] = (f32x4){bias20, bias20, bias20, bias20};
    acc2[mf][1] = (f32x4){bias21, bias21, bias21, bias21};
  }
  #pragma unroll
  for (int ks = 0; ks < 4; ++ks)
    #pragma unroll
    for (int mf = 0; mf < 4; ++mf) {
      int r = mf * 16 + l16;
      int lofs = (r * 256 + ks * 64 + wq * 16) ^ ((r & 7) << 4);
      bf16x8 av = __builtin_bit_cast(bf16x8, *(const int4*)(Hlds + lofs));
      acc2[mf][0] = __builtin_amdgcn_mfma_f32_16x16x32_bf16(av, bf2r[ks][0], acc2[mf][0], 0, 0, 0);
      acc2[mf][1] = __builtin_amdgcn_mfma_f32_16x16x32_bf16(av, bf2r[ks][1], acc2[mf][1], 0, 0, 0);
    }

  #pragma unroll
  for (int mf = 0; mf < 4; ++mf)
    #pragma unroll
    for (int nf = 0; nf < 2; ++nf) {
      int c = wave * 32 + nf * 16 + l16;
      #pragma unroll
      for (int rg = 0; rg < 4; ++rg) {
        int r = mf * 16 + wq * 4 + rg;
        outp[(size_t)(eb + r) * 128 + c] = acc2[mf][nf][rg];
      }
    }
}

extern "C" void kernel_launch(void* const* d_in, const int* in_sizes, int n_in,
                              void* d_out, int out_size, void* d_ws, size_t ws_size,
                              hipStream_t stream) {
  const float* x  = (const float*)d_in[0];
  const float* ea = (const float*)d_in[1];
  const int* eidx = (const int*)d_in[2];
  const float* W1 = (const float*)d_in[3];
  const float* b1 = (const float*)d_in[4];
  const float* W2 = (const float*)d_in[5];
  const float* b2 = (const float*)d_in[6];
  float* outp = (float*)d_out;

  const int E = in_sizes[2] / 2;
  const int nnodes = in_sizes[0] / 128;
  const int ntiles = E / BM;

  unsigned short* Bp1 = (unsigned short*)d_ws;           // 64 KB
  unsigned short* Bp2 = Bp1 + 32768;                     // 32 KB
  unsigned short* xb  = (unsigned short*)((char*)d_ws + 98304);
  const size_t need = 98304 + (size_t)nnodes * 128 * 2;

  pack_w_kernel<<<192, 256, 0, stream>>>(W1, W2, Bp1, Bp2);

  if (ws_size >= need) {
    int n8 = nnodes * 128 / 8;
    convert_x_kernel<<<(n8 + 255) / 256, 256, 0, stream>>>(x, xb, n8);
    edge_staged<<<ntiles, 256, 0, stream>>>(xb, ea, eidx, W1, b1, b2, Bp1, Bp2, outp, E);
  } else {
    edge_main_f32<<<ntiles, 256, 0, stream>>>(x, ea, eidx, W1, b1, b2, Bp1, Bp2, outp, E);
  }
}